// Round 4
// baseline (280.922 us; speedup 1.0000x reference)
//
#include <hip/hip_runtime.h>
#include <hip/hip_fp16.h>

// ---------------------------------------------------------------------------
// 3-layer GCN + linear head.  N=50000, E=800000, D=128.
// v4: dispatch-count + fusion round.  6 dispatches (was 10+memset):
//   memset, build(gemm1+edge atomics), fill, fused(agg+gemm) x3.
//  * k_agg_gemm: agg 64 nodes -> z in LDS -> __syncthreads -> z@W via MFMA.
//    Removes z16 global round-trip (25.6MB/layer), 3 gemm dispatches, and
//    k_dinv (agg/fill read packed cnt8 and rsqrt in place).
//  * agg inside fused kernel: 2 nodes per wave concurrently (half-wave per
//    node), ev row via 2x uint4, 8 gathers in flight per lane -> per-CU
//    MLP parity with v3 despite LDS-capped occupancy (2 blocks/CU).
// [v2 lesson: agg is LATENCY-bound; never trade bytes-per-load/MLP for
//  cache locality.  v3 lesson: ~6us/dispatch gap -> fuse aggressively.]
// ---------------------------------------------------------------------------

#define D 128
#define CNT64_STRIDE 8    // one u64 counter per 64 B cache line
#define SLOTS 64          // fixed CSR capacity per node (P(deg>=64) ~ 1e-13)

typedef __attribute__((ext_vector_type(8))) _Float16 half8;
typedef __attribute__((ext_vector_type(4))) float floatx4;

__device__ __forceinline__ void fma8(float acc[8], float v, uint4 q) {
    union { uint4 uu; __half2 h2[4]; } U; U.uu = q;
    float2 f0 = __half22float2(U.h2[0]);
    float2 f1 = __half22float2(U.h2[1]);
    float2 f2 = __half22float2(U.h2[2]);
    float2 f3 = __half22float2(U.h2[3]);
    acc[0] = fmaf(v, f0.x, acc[0]); acc[1] = fmaf(v, f0.y, acc[1]);
    acc[2] = fmaf(v, f1.x, acc[2]); acc[3] = fmaf(v, f1.y, acc[3]);
    acc[4] = fmaf(v, f2.x, acc[4]); acc[5] = fmaf(v, f2.y, acc[5]);
    acc[6] = fmaf(v, f3.x, acc[6]); acc[7] = fmaf(v, f3.y, acc[7]);
}

// ---- GEMM1 body (A fp32 row-major): C16 = x @ W1, 128 rows/block ---------
// 8 waves x 16 rows, v_mfma_f32_16x16x32_f16 (layouts m89/m91).
__device__ __forceinline__ void gemm1_body(int bid, const float* A32p,
                                           const float* W, __half* C16, int N) {
    __shared__ _Float16 Wl[128][136];
    int tid = threadIdx.x;

#pragma unroll
    for (int j = 0; j < 32; j++) {
        int e = tid + j * 512;          // 16384 elements
        Wl[e & 127][e >> 7] = (_Float16)W[e];
    }
    __syncthreads();

    int wave = tid >> 6, lane = tid & 63;
    int m = lane & 15, q = lane >> 4;
    int R0 = bid * 128 + wave * 16;

    floatx4 acc[8];
#pragma unroll
    for (int ct = 0; ct < 8; ct++) acc[ct] = (floatx4){0.f, 0.f, 0.f, 0.f};

    int arow = R0 + m;
    bool rok = arow < N;

#pragma unroll
    for (int kk = 0; kk < 4; kk++) {
        half8 a = {0, 0, 0, 0, 0, 0, 0, 0};
        if (rok) {
            const float* p = &A32p[(size_t)arow * 128 + kk * 32 + q * 8];
            float4 f0 = *(const float4*)p;
            float4 f1 = *(const float4*)(p + 4);
            a[0] = (_Float16)f0.x; a[1] = (_Float16)f0.y;
            a[2] = (_Float16)f0.z; a[3] = (_Float16)f0.w;
            a[4] = (_Float16)f1.x; a[5] = (_Float16)f1.y;
            a[6] = (_Float16)f1.z; a[7] = (_Float16)f1.w;
        }
#pragma unroll
        for (int ct = 0; ct < 8; ct++) {
            half8 b = *(const half8*)&Wl[ct * 16 + m][kk * 32 + q * 8];
            acc[ct] = __builtin_amdgcn_mfma_f32_16x16x32_f16(a, b, acc[ct], 0, 0, 0);
        }
    }

#pragma unroll
    for (int r = 0; r < 4; r++) {
        int row = R0 + q * 4 + r;
        if (row >= N) continue;
#pragma unroll
        for (int ct = 0; ct < 8; ct++)
            C16[(size_t)row * 128 + ct * 16 + m] = __float2half_rn(acc[ct][r]);
    }
}

// ---- fused: blocks [0,gg) = GEMM1 (x@W1 -> y16); [ggp,..) = edge atomics --
__global__ __launch_bounds__(512) void k_build_gemm1(const float* __restrict__ x,
                                                     const float* __restrict__ W1,
                                                     __half* __restrict__ y16,
                                                     const int* __restrict__ dst,
                                                     const float* __restrict__ w,
                                                     unsigned long long* __restrict__ cnt8,
                                                     int* __restrict__ loc,
                                                     int N, int E, int gg, int ggp) {
    int b = (int)blockIdx.x;
    if (b < gg) {
        gemm1_body(b, x, W1, y16, N);
        return;
    }
    if (b < ggp) return;
    int e = (b - ggp) * 512 + threadIdx.x;
    if (e < E) {
        int d = dst[e];
        unsigned int wq = __float2uint_rn(w[e] * 32767.0f);
        unsigned long long old =
            atomicAdd(&cnt8[(size_t)d * CNT64_STRIDE], (1ull << 32) | (unsigned long long)wq);
        loc[e] = (int)(old >> 32);
    }
}

// ---- CSR fill (fixed slots): ev[d*64+loc] = (q15 << 17) | src -------------
// dinv computed in place from the packed counters (low u32 = q15 wsum).
__global__ __launch_bounds__(256) void k_fill(const int* __restrict__ ei,
                                              const float* __restrict__ w,
                                              const unsigned int* __restrict__ wsum32,
                                              const int* __restrict__ loc,
                                              unsigned int* __restrict__ ev, int E) {
    int e = blockIdx.x * 256 + threadIdx.x;
    if (e < E) {
        int s = ei[e];
        int d = ei[E + e];
        float dvs = rsqrtf(1.0f + (float)wsum32[(size_t)s * 16] * (1.0f / 32767.0f));
        float dvd = rsqrtf(1.0f + (float)wsum32[(size_t)d * 16] * (1.0f / 32767.0f));
        float val = w[e] * dvs * dvd;   // in [0,1)
        unsigned int wq = __float2uint_rn(val * 32767.0f);
        ev[(size_t)d * SLOTS + loc[e]] = (wq << 17) | (unsigned int)s;
    }
}

// ---- fused agg + GEMM: 64 nodes/block, 512 threads (8 waves) --------------
// Phase 1 (agg): wave w handles nodes w*8..w*8+7 as 4 sequential PAIRS;
//   half-wave (h=lane>>5) per node, groups g2 (slots base+g2*8..+7) x
//   sl (features sl*8..+7).  Per lane: 2x uint4 ev load + 8 uint4 gathers
//   in flight.  z = relu?(agg + bagg + di^2*self) -> Z in LDS (fp16).
// Phase 2 (gemm): C = Z @ W; wave w: row-group w>>1 (16 rows), col-half w&1.
__global__ __launch_bounds__(512, 4) void k_agg_gemm(
    const __half* __restrict__ yin,
    const unsigned long long* __restrict__ cnt8,
    const unsigned int* __restrict__ ev,
    const float* __restrict__ bagg,
    const float* __restrict__ W,
    const float* __restrict__ bout,   // final bias (bl) or null
    float* __restrict__ C32,          // final fp32 out or null
    __half* __restrict__ yout,        // next-layer y16 or null
    int N, int relu) {
    __shared__ _Float16 Wl[128][136];
    __shared__ _Float16 Z[64][136];
    int tid = threadIdx.x;

    // stage W transposed (read once per block; barrier below covers it)
#pragma unroll
    for (int j = 0; j < 32; j++) {
        int e = tid + j * 512;          // 16384 elements
        Wl[e & 127][e >> 7] = (_Float16)W[e];
    }

    int wave = tid >> 6, lane = tid & 63;
    int h = lane >> 5;          // node within pair
    int l5 = lane & 31;
    int g2 = l5 >> 4;           // slot-parity half (slots g2*8 + u)
    int sl = l5 & 15;           // feature slice: 8 fp16 at sl*8

    int R0 = (int)blockIdx.x * 64;

    float4 b0 = *(const float4*)&bagg[sl * 8];
    float4 b1 = *(const float4*)&bagg[sl * 8 + 4];

#pragma unroll 1
    for (int pair = 0; pair < 4; pair++) {
        int nloc = wave * 8 + pair * 2 + h;
        int i = R0 + nloc;
        bool valid = i < N;

        unsigned long long pk = valid ? cnt8[(size_t)i * CNT64_STRIDE] : 0ull;
        int cnt = (int)(pk >> 32);
        float di = rsqrtf(1.0f + (float)(unsigned int)pk * (1.0f / 32767.0f));

        const unsigned int* evp = ev + (size_t)(valid ? i : 0) * SLOTS;

        float acc[8];
#pragma unroll
        for (int j = 0; j < 8; j++) acc[j] = 0.f;

        int cntmax = max(cnt, __shfl_xor(cnt, 32, 64));
        for (int base = 0; base < cntmax; base += 16) {
            uint4 ea = *(const uint4*)&evp[base + g2 * 8];
            uint4 eb = *(const uint4*)&evp[base + g2 * 8 + 4];
            unsigned int p[8] = {ea.x, ea.y, ea.z, ea.w, eb.x, eb.y, eb.z, eb.w};
            float v[8];
            uint4 q4[8];
#pragma unroll
            for (int u = 0; u < 8; u++) {
                bool ok = (base + g2 * 8 + u) < cnt;
                v[u] = ok ? (float)(p[u] >> 17) * (1.0f / 32767.0f) : 0.0f;
                int r = min((int)(p[u] & 0x1FFFFu), N - 1);   // in-bounds always
                q4[u] = *(const uint4*)&yin[(size_t)r * D + sl * 8];
            }
#pragma unroll
            for (int u = 0; u < 8; u++) fma8(acc, v[u], q4[u]);
        }

        // fold the two slot-halves (lane ^16 stays within the 32-lane node)
#pragma unroll
        for (int j = 0; j < 8; j++) acc[j] += __shfl_xor(acc[j], 16, 64);

        if (g2 == 0) {
            float o[8];
            if (valid) {
                float di2 = di * di;
                union { uint4 u; __half2 h2[4]; } S;
                S.u = *(const uint4*)&yin[(size_t)i * D + sl * 8];
                float2 s0 = __half22float2(S.h2[0]);
                float2 s1 = __half22float2(S.h2[1]);
                float2 s2 = __half22float2(S.h2[2]);
                float2 s3 = __half22float2(S.h2[3]);
                o[0] = b0.x + acc[0] + di2 * s0.x;
                o[1] = b0.y + acc[1] + di2 * s0.y;
                o[2] = b0.z + acc[2] + di2 * s1.x;
                o[3] = b0.w + acc[3] + di2 * s1.y;
                o[4] = b1.x + acc[4] + di2 * s2.x;
                o[5] = b1.y + acc[5] + di2 * s2.y;
                o[6] = b1.z + acc[6] + di2 * s3.x;
                o[7] = b1.w + acc[7] + di2 * s3.y;
                if (relu) {
#pragma unroll
                    for (int j = 0; j < 8; j++) o[j] = fmaxf(o[j], 0.f);
                }
            } else {
#pragma unroll
                for (int j = 0; j < 8; j++) o[j] = 0.f;
            }
            union { uint4 u; __half2 h2[4]; } O;
            O.h2[0] = __float22half2_rn(make_float2(o[0], o[1]));
            O.h2[1] = __float22half2_rn(make_float2(o[2], o[3]));
            O.h2[2] = __float22half2_rn(make_float2(o[4], o[5]));
            O.h2[3] = __float22half2_rn(make_float2(o[6], o[7]));
            *(uint4*)&Z[nloc][sl * 8] = O.u;
        }
    }

    __syncthreads();

    // ---- phase 2: C[R0..R0+63] = Z @ W ------------------------------------
    int m = lane & 15, q = lane >> 4;
    int rg = wave >> 1;         // row group (16 rows)
    int ch = wave & 1;          // column half (64 cols)

    floatx4 acc2[4];
#pragma unroll
    for (int ct = 0; ct < 4; ct++) acc2[ct] = (floatx4){0.f, 0.f, 0.f, 0.f};

#pragma unroll
    for (int kk = 0; kk < 4; kk++) {
        half8 a = *(const half8*)&Z[rg * 16 + m][kk * 32 + q * 8];
#pragma unroll
        for (int ct = 0; ct < 4; ct++) {
            half8 b = *(const half8*)&Wl[ch * 64 + ct * 16 + m][kk * 32 + q * 8];
            acc2[ct] = __builtin_amdgcn_mfma_f32_16x16x32_f16(a, b, acc2[ct], 0, 0, 0);
        }
    }

#pragma unroll
    for (int r = 0; r < 4; r++) {
        int row = R0 + rg * 16 + q * 4 + r;
        if (row >= N) continue;
#pragma unroll
        for (int ct = 0; ct < 4; ct++) {
            int col = ch * 64 + ct * 16 + m;
            float v = acc2[ct][r];
            if (yout) yout[(size_t)row * D + col] = __float2half_rn(v);
            else      C32[(size_t)row * D + col] = v + bout[col];
        }
    }
}

// ---------------------------------------------------------------------------
extern "C" void kernel_launch(void* const* d_in, const int* in_sizes, int n_in,
                              void* d_out, int out_size, void* d_ws, size_t ws_size,
                              hipStream_t stream) {
    const float* x  = (const float*)d_in[0];
    const int*   ei = (const int*)d_in[1];     // [2,E]: src row then dst row
    const float* ew = (const float*)d_in[2];
    const float* W1 = (const float*)d_in[3];
    const float* b1 = (const float*)d_in[4];
    const float* W2 = (const float*)d_in[5];
    const float* b2 = (const float*)d_in[6];
    const float* W3 = (const float*)d_in[7];
    const float* b3 = (const float*)d_in[8];
    const float* Wl = (const float*)d_in[9];
    const float* bl = (const float*)d_in[10];

    int N = in_sizes[0] / D;    // 50000
    int E = in_sizes[2];        // 800000

    char* ws = (char*)d_ws;
    size_t off = 0;
    auto alloc = [&](size_t bytes) {
        void* p = ws + off;
        off = (off + bytes + 255) & ~(size_t)255;
        return p;
    };
    unsigned long long* cnt8 = (unsigned long long*)alloc((size_t)N * 64); // padded
    int*    loc  = (int*)alloc((size_t)E * 4);
    unsigned int* ev = (unsigned int*)alloc((size_t)N * SLOTS * 4);  // 12.8MB
    __half* yA   = (__half*)alloc((size_t)N * D * 2);   // row-major [N][128]
    __half* yB   = (__half*)alloc((size_t)N * D * 2);   // row-major [N][128]

    int nbE    = (E + 255) / 256;     // 3125 (fill)
    int nbE512 = (E + 511) / 512;     // 1563 (build edge part)
    int gg     = (N + 127) / 128;     // 391 GEMM1 blocks
    int ggp    = (gg + 7) & ~7;       // 392
    int nf     = (N + 63) / 64;       // 782 fused blocks

    hipMemsetAsync(cnt8, 0, (size_t)N * 64, stream);
    k_build_gemm1<<<ggp + nbE512, 512, 0, stream>>>(x, W1, yA, ei + E, ew,
                                                    cnt8, loc, N, E, gg, ggp);
    k_fill<<<nbE, 256, 0, stream>>>(ei, ew, (const unsigned int*)cnt8, loc, ev, E);

    k_agg_gemm<<<nf, 512, 0, stream>>>(yA, cnt8, ev, b1, W2, nullptr, nullptr, yB, N, 1);
    k_agg_gemm<<<nf, 512, 0, stream>>>(yB, cnt8, ev, b2, W3, nullptr, nullptr, yA, N, 1);
    k_agg_gemm<<<nf, 512, 0, stream>>>(yA, cnt8, ev, b3, Wl, bl, (float*)d_out, nullptr, N, 0);
}